// Round 15
// baseline (104.712 us; speedup 1.0000x reference)
//
#include <hip/hip_runtime.h>
#include <cstdint>

#define BB 16
#define NN 65536
#define DD 32
#define KK 64
#define DELTA_V 0.5f
#define DELTA_D 1.5f

typedef short bf16x8 __attribute__((ext_vector_type(8)));
typedef float f32x16 __attribute__((ext_vector_type(16)));

__device__ __forceinline__ short f2bf(float x) {
    union { float f; unsigned u; } v; v.f = x;
    const unsigned r = v.u + 0x7FFFu + ((v.u >> 16) & 1u);  // RNE
    return (short)(r >> 16);
}

// ---------------------------------------------------------------------------
// Kernel 1: phase A = wide float4 streaming touch (warms L3 at true
// cold-read BW, k_pull's proven pattern); phase B = R11 one-hot MFMA
// segment-sum, now reading L3-hot data (R12-measured 10.6us).
// ---------------------------------------------------------------------------
#define K1_BPB 64                    // blocks per batch -> grid 1024
#define K1_PPB 1024                  // points per block (4 waves x 256)

__global__ __launch_bounds__(256, 2) void k_accum(
    const float* __restrict__ emb, const int* __restrict__ ids,
    const int* __restrict__ mask, float* __restrict__ parts,
    float* __restrict__ pcnt)
{
    __shared__ float tbl[4][64][32];  // 32 KB, used only at the end
    __shared__ float lc2[4][64];
    const int tid  = threadIdx.x;
    const int w    = tid >> 6, lane = tid & 63;
    const int half = lane >> 5, d32 = lane & 31;
    const int b    = blockIdx.x >> 6;
    const int blk  = blockIdx.x & 63;
    const size_t pw = (size_t)b * NN + (size_t)blk * K1_PPB + (size_t)w * 256;

    // ======== phase A: streaming L3-warm touch (proven-coalesced float4) ====
    {
        const float4* ep4 = (const float4*)(emb + pw * DD);   // 2048 float4/wave
        float sx = 0.f, sy = 0.f, sz = 0.f, sw = 0.f;
#pragma unroll
        for (int u = 0; u < 4; ++u) {
            float4 t[8];
#pragma unroll
            for (int k = 0; k < 8; ++k) t[k] = ep4[u * 512 + k * 64 + lane];
#pragma unroll
            for (int k = 0; k < 8; ++k) {
                sx += t[k].x; sy += t[k].y; sz += t[k].z; sw += t[k].w;
            }
        }
        // keep the touch alive without using its value (no DCE)
        asm volatile("" :: "v"(sx), "v"(sy), "v"(sz), "v"(sw));
    }

    // ======== phase B: one-hot MFMA segment-sum (R11, absmax-0-proven) ======
    f32x16 acc0 = {}, acc1 = {};
    int c0 = 0, c1 = 0;
    const int m0 = d32, m1 = d32 + 32;

    const int* idsb = ids + pw;
    const int* mskb = mask + pw;
    const float* eb = emb + (pw + (size_t)half * 8) * DD + d32;

    float xa[32], xb[32];
    int idr, mkr;
#pragma unroll
    for (int j = 0; j < 32; ++j)
        xa[j] = eb[(size_t)(((j >> 3) * 16) + (j & 7)) * DD];
    idr = idsb[lane]; mkr = mskb[lane];

#pragma unroll
    for (int s = 0; s < 4; ++s) {                 // 4 stages of 64 points
        int idr2 = 0, mkr2 = 0;
        if (s < 3) {                              // prefetch next stage
            const float* eb2 = eb + (size_t)(s + 1) * 64 * DD;
#pragma unroll
            for (int j = 0; j < 32; ++j)
                xb[j] = eb2[(size_t)(((j >> 3) * 16) + (j & 7)) * DD];
            idr2 = idsb[(s + 1) * 64 + lane];
            mkr2 = mskb[(s + 1) * 64 + lane];
        }
        const int vid = (mkr != 0 && (unsigned)idr < KK) ? idr : -1;
#pragma unroll
        for (int q = 0; q < 4; ++q) {             // 16-point MFMA pairs
            bf16x8 bfB, a0, a1;
#pragma unroll
            for (int e = 0; e < 8; ++e) {
                bfB[e] = f2bf(xa[q * 8 + e]);
                const int s_lo = __builtin_amdgcn_readlane(vid, q * 16 + e);
                const int s_hi = __builtin_amdgcn_readlane(vid, q * 16 + 8 + e);
                const int sel  = half ? s_hi : s_lo;
                const bool h0 = (sel == m0), h1 = (sel == m1);
                a0[e] = h0 ? (short)0x3F80 : (short)0;   // bf16 1.0
                a1[e] = h1 ? (short)0x3F80 : (short)0;
                c0 += h0 ? 1 : 0;
                c1 += h1 ? 1 : 0;
            }
            acc0 = __builtin_amdgcn_mfma_f32_32x32x16_bf16(a0, bfB, acc0, 0, 0, 0);
            acc1 = __builtin_amdgcn_mfma_f32_32x32x16_bf16(a1, bfB, acc1, 0, 0, 0);
        }
        if (s < 3) {
#pragma unroll
            for (int j = 0; j < 32; ++j) xa[j] = xb[j];
            idr = idr2; mkr = mkr2;
        }
    }

    // park C fragments (verified C/D layout) and 4-wave block reduce
#pragma unroll
    for (int r = 0; r < 16; ++r) {
        const int mrow = (r & 3) + 8 * (r >> 2) + 4 * half;
        tbl[w][mrow][d32]      = acc0[r];
        tbl[w][32 + mrow][d32] = acc1[r];
    }
    c0 += __shfl_down(c0, 32);
    c1 += __shfl_down(c1, 32);
    if (lane < 32) { lc2[w][lane] = (float)c0; lc2[w][lane + 32] = (float)c1; }
    __syncthreads();

    float* pb = parts + (size_t)blockIdx.x * 2048;
    for (int i = tid; i < 2048; i += 256) {
        const int row = i >> 5, col = i & 31;
        pb[i] = tbl[0][row][col] + tbl[1][row][col]
              + tbl[2][row][col] + tbl[3][row][col];
    }
    if (tid < KK)
        pcnt[(size_t)blockIdx.x * KK + tid] =
            lc2[0][tid] + lc2[1][tid] + lc2[2][tid] + lc2[3][tid];
}

// ---------------------------------------------------------------------------
// Kernel 2: parallel mean-reduce (R14-proven). Also zeroes the K3 ticket.
// ---------------------------------------------------------------------------
__global__ __launch_bounds__(256) void k_mid(
    const float* __restrict__ parts, const float* __restrict__ pcnt,
    float* __restrict__ mu, int* bar)
{
    const int gb  = blockIdx.x;          // 0..255
    const int b   = gb >> 4, seg = gb & 15;
    const int tid = threadIdx.x;
    __shared__ float red2[2][128];
    __shared__ float rc4[4];
    if (gb == 0 && tid == 0) bar[0] = 0;         // ticket reset for K3

    const int k0 = seg * 4;
    {   // counts: wave w -> k = k0 + w
        const int w = tid >> 6, lane = tid & 63;
        float cv = pcnt[((size_t)(b * K1_BPB + lane)) * KK + k0 + w];
        for (int off = 32; off; off >>= 1) cv += __shfl_down(cv, off);
        if (lane == 0) {
            mu[((size_t)b * KK + k0 + w) * 36 + 32] = cv;
            const float rc = 1.f / fmaxf(cv, 1.f);
            mu[((size_t)b * KK + k0 + w) * 36 + 33] = rc;
            rc4[w] = rc;
        }
    }
    const int e  = seg * 128 + (tid & 127);
    const int jh = tid >> 7;             // 0 / 1
    float s = 0.f;
    const float* pp = parts + ((size_t)(b * K1_BPB + jh * 32)) * 2048 + e;
#pragma unroll 4
    for (int j = 0; j < 32; ++j) s += pp[(size_t)j * 2048];
    red2[jh][tid & 127] = s;
    __syncthreads();
    if (tid < 128) {
        const int k = e >> 5;
        mu[((size_t)b * KK + k) * 36 + (e & 31)] =
            (red2[0][tid] + red2[1][tid]) * rc4[k - k0];
    }
}

// ---------------------------------------------------------------------------
// Kernel 3: pull pass + designated-block push/reg + last-ticket final
// (R14-proven).
// ---------------------------------------------------------------------------
#define K2_BPB 64
#define K2_PTS 1024
#define GRID3 (BB * K2_BPB)              // 1024

__global__ __launch_bounds__(256) void k_pull_final(
    const float* __restrict__ emb, const int* __restrict__ ids,
    const int* __restrict__ mask, const float* __restrict__ mu,
    float* varpart, float* aux, int* bar, float* __restrict__ out)
{
    __shared__ float smu[KK][36];
    __shared__ float red[4];
    __shared__ float part[256];
    __shared__ float sf[4][BB];
    __shared__ int s_last;
    const int tid = threadIdx.x;
    const int w = tid >> 6, lane = tid & 63;
    const int pl = lane >> 3;
    const int pc = lane & 7;
    const int b   = blockIdx.x >> 6;
    const int blk = blockIdx.x & 63;

    const float* mub = mu + (size_t)b * KK * 36;
    for (int i = tid; i < KK * 36; i += 256) ((float*)smu)[i] = mub[i];
    __syncthreads();

    // ---- designated block per batch: reg + push losses from smu ----
    if (blk == 0) {
        float ninst = 0.f;
        if (tid < KK) {
            const float c = smu[tid][32];
            const float pres = (c > 0.f) ? 1.f : 0.f;
            float sq = 0.f;
#pragma unroll
            for (int d = 0; d < DD; ++d) { const float m = smu[tid][d]; sq = fmaf(m, m, sq); }
            float nm = ((sq > 0.f) ? sqrtf(sq) : 0.f) * pres;
            float pn = pres;
            for (int off = 32; off; off >>= 1) {
                pn += __shfl_down(pn, off);
                nm += __shfl_down(nm, off);
            }
            if (tid == 0) {
                ninst = pn;
                aux[b]      = nm / fmaxf(pn, 1.f);   // reg_b
                aux[32 + b] = pn;                    // num_inst
            }
        }
        float acc = 0.f;
        for (int idx = tid; idx < KK * KK; idx += 256) {
            const int i = idx >> 6, j = idx & 63;
            if (i < j && smu[i][32] > 0.f && smu[j][32] > 0.f) {
                float dsq = 0.f;
#pragma unroll
                for (int d = 0; d < DD; ++d) {
                    const float df = smu[i][d] - smu[j][d];
                    dsq = fmaf(df, df, dsq);
                }
                const float pd = (dsq > 0.f) ? sqrtf(dsq) : 0.f;
                const float pen = fmaxf(2.f * DELTA_D - pd, 0.f);
                acc = fmaf(pen, pen, acc);
            }
        }
        for (int off = 32; off; off >>= 1) acc += __shfl_down(acc, off);
        if ((tid & 63) == 0) red[tid >> 6] = acc;
        __syncthreads();
        if (tid == 0) {
            const float tot = red[0] + red[1] + red[2] + red[3];
            const float ni = aux[32 + b];
            const float np = ni * (ni - 1.f) * 0.5f;
            aux[16 + b] = tot / fmaxf(np, 1.f);      // dist_b
        }
        __syncthreads();                  // red free for pull reuse
    }

    // ---- pull pass (R11-proven, fully coalesced) ----
    const size_t p0 = (size_t)b * NN + (size_t)blk * K2_PTS + (size_t)w * 256;
    float accv = 0.f;
    for (int t = 0; t < 4; ++t) {
        const size_t pt0 = p0 + t * 64;
        const int idr = ids[pt0 + lane];
        const int mkr = mask[pt0 + lane];
        const int vid = (mkr != 0 && (unsigned)idr < KK) ? idr : -1;
        const float4* ep4 = (const float4*)(emb + pt0 * DD);
#pragma unroll
        for (int g = 0; g < 8; ++g) {
            const float4 x = ep4[g * 64 + lane];
            const int sid = __shfl(vid, g * 8 + pl);
            const int row = (sid >= 0) ? sid : 0;
            const float4 m4 = *(const float4*)&smu[row][4 * pc];
            float a = x.x - m4.x; float dsq = a * a;
            a = x.y - m4.y; dsq = fmaf(a, a, dsq);
            a = x.z - m4.z; dsq = fmaf(a, a, dsq);
            a = x.w - m4.w; dsq = fmaf(a, a, dsq);
            dsq += __shfl_xor(dsq, 1);
            dsq += __shfl_xor(dsq, 2);
            dsq += __shfl_xor(dsq, 4);
            if (pc == 0 && sid >= 0) {
                const float dist = (dsq > 0.f) ? sqrtf(dsq) : 0.f;
                float pen = fmaxf(dist - DELTA_V, 0.f);
                accv = fmaf(pen * pen, smu[row][33], accv);
            }
        }
    }
    for (int off = 32; off; off >>= 1) accv += __shfl_down(accv, off);
    if (lane == 0) red[w] = accv;
    __syncthreads();
    if (tid == 0)
        varpart[blockIdx.x] = red[0] + red[1] + red[2] + red[3];

    // ---- last-arrival ticket: combine (R9-proven protocol) ----
    if (tid == 0) {
        const int ret = __hip_atomic_fetch_add(bar, 1, __ATOMIC_RELEASE,
                                               __HIP_MEMORY_SCOPE_AGENT);
        s_last = (ret == GRID3 - 1) ? 1 : 0;
        if (s_last)
            (void)__hip_atomic_load(bar, __ATOMIC_ACQUIRE,
                                    __HIP_MEMORY_SCOPE_AGENT);
    }
    __syncthreads();
    if (s_last) {
        {   // each thread sums 4 varpart entries (coalesced float4)
            const float4 v4 = ((const float4*)varpart)[tid];
            part[tid] = v4.x + v4.y + v4.z + v4.w;
        }
        __syncthreads();
        if (tid < BB) {
            float vs = 0.f;
#pragma unroll
            for (int j = 0; j < 16; ++j) vs += part[tid * 16 + j];
            const float ni = aux[32 + tid];
            sf[0][tid] = vs / fmaxf(ni, 1.f);
            sf[1][tid] = (ni >= 2.f) ? 1.f : 0.f;
            sf[2][tid] = aux[tid];
            sf[3][tid] = aux[16 + tid];
        }
        __syncthreads();
        if (tid == 0) {
            float denom = 0.f, v = 0.f, d = 0.f, r = 0.f;
            for (int bb = 0; bb < BB; ++bb) {
                const float vb = sf[1][bb];
                denom += vb;
                v += sf[0][bb] * vb;
                d += sf[3][bb] * vb;
                r += sf[2][bb] * vb;
            }
            denom = fmaxf(denom, 1.f);
            v /= denom; d /= denom; r /= denom;
            out[0] = v + d + 0.001f * r;   // ALPHA=BETA=1, GAMMA=0.001
            out[1] = v;
            out[2] = d;
            out[3] = r;
        }
    }
}

// ---------------------------------------------------------------------------
extern "C" void kernel_launch(void* const* d_in, const int* in_sizes, int n_in,
                              void* d_out, int out_size, void* d_ws, size_t ws_size,
                              hipStream_t stream)
{
    const float* emb  = (const float*)d_in[0];
    const int*   ids  = (const int*)d_in[1];
    const int*   mask = (const int*)d_in[2];   // bool widened to int32

    float* ws      = (float*)d_ws;
    float* parts   = ws;                                        // 1024*2048
    float* pcnt    = parts + (size_t)BB * K1_BPB * KK * DD;     // 1024*64
    float* mu      = pcnt + (size_t)BB * K1_BPB * KK;           // 16*64*36
    float* varpart = mu + (size_t)BB * KK * 36;                 // 1024
    float* aux     = varpart + GRID3;                           // 48
    int*   bar     = (int*)(aux + 64);                          // 1 ticket

    k_accum<<<BB * K1_BPB, 256, 0, stream>>>(emb, ids, mask, parts, pcnt);
    k_mid<<<256, 256, 0, stream>>>(parts, pcnt, mu, bar);
    k_pull_final<<<GRID3, 256, 0, stream>>>(emb, ids, mask, mu, varpart,
                                            aux, bar, (float*)d_out);
}

// Round 16
// 86.470 us; speedup vs baseline: 1.2110x; 1.2110x over previous
//
#include <hip/hip_runtime.h>
#include <cstdint>

#define BB 16
#define NN 65536
#define DD 32
#define KK 64
#define DELTA_V 0.5f
#define DELTA_D 1.5f

typedef short bf16x8 __attribute__((ext_vector_type(8)));
typedef float f32x16 __attribute__((ext_vector_type(16)));

__device__ __forceinline__ short f2bf(float x) {
    union { float f; unsigned u; } v; v.f = x;
    const unsigned r = v.u + 0x7FFFu + ((v.u >> 16) & 1u);  // RNE
    return (short)(r >> 16);
}

// ---------------------------------------------------------------------------
// Kernel 1: one-hot MFMA segment-sum (R11 structure, absmax-0-proven).
// __launch_bounds__(256, 1): full 256-VGPR budget so the 64-load dual-stage
// prefetch (xa[32]+xb[32]) actually stays in registers (R12 measured the
// (256,4) build squeezed to 64 VGPRs -> ~8 loads in flight).
// ---------------------------------------------------------------------------
#define K1_BPB 64                    // blocks per batch -> grid 1024
#define K1_PPB 1024                  // points per block (4 waves x 256)

__global__ __launch_bounds__(256, 1) void k_accum(
    const float* __restrict__ emb, const int* __restrict__ ids,
    const int* __restrict__ mask, float* __restrict__ parts,
    float* __restrict__ pcnt)
{
    __shared__ float tbl[4][64][32];  // 32 KB, used only at the end
    __shared__ float lc2[4][64];
    const int tid  = threadIdx.x;
    const int w    = tid >> 6, lane = tid & 63;
    const int half = lane >> 5, d32 = lane & 31;
    const int b    = blockIdx.x >> 6;
    const int blk  = blockIdx.x & 63;
    const size_t pw = (size_t)b * NN + (size_t)blk * K1_PPB + (size_t)w * 256;

    f32x16 acc0 = {}, acc1 = {};
    int c0 = 0, c1 = 0;
    const int m0 = d32, m1 = d32 + 32;

    const int* idsb = ids + pw;
    const int* mskb = mask + pw;
    const float* eb = emb + (pw + (size_t)half * 8) * DD + d32;

    float xa[32], xb[32];
    int idr, mkr;
#pragma unroll
    for (int j = 0; j < 32; ++j)
        xa[j] = eb[(size_t)(((j >> 3) * 16) + (j & 7)) * DD];
    idr = idsb[lane]; mkr = mskb[lane];

#pragma unroll
    for (int s = 0; s < 4; ++s) {                 // 4 stages of 64 points
        int idr2 = 0, mkr2 = 0;
        if (s < 3) {                              // prefetch next stage
            const float* eb2 = eb + (size_t)(s + 1) * 64 * DD;
#pragma unroll
            for (int j = 0; j < 32; ++j)
                xb[j] = eb2[(size_t)(((j >> 3) * 16) + (j & 7)) * DD];
            idr2 = idsb[(s + 1) * 64 + lane];
            mkr2 = mskb[(s + 1) * 64 + lane];
        }
        const int vid = (mkr != 0 && (unsigned)idr < KK) ? idr : -1;
#pragma unroll
        for (int q = 0; q < 4; ++q) {             // 16-point MFMA pairs
            bf16x8 bfB, a0, a1;
#pragma unroll
            for (int e = 0; e < 8; ++e) {
                bfB[e] = f2bf(xa[q * 8 + e]);
                const int s_lo = __builtin_amdgcn_readlane(vid, q * 16 + e);
                const int s_hi = __builtin_amdgcn_readlane(vid, q * 16 + 8 + e);
                const int sel  = half ? s_hi : s_lo;
                const bool h0 = (sel == m0), h1 = (sel == m1);
                a0[e] = h0 ? (short)0x3F80 : (short)0;   // bf16 1.0
                a1[e] = h1 ? (short)0x3F80 : (short)0;
                c0 += h0 ? 1 : 0;
                c1 += h1 ? 1 : 0;
            }
            acc0 = __builtin_amdgcn_mfma_f32_32x32x16_bf16(a0, bfB, acc0, 0, 0, 0);
            acc1 = __builtin_amdgcn_mfma_f32_32x32x16_bf16(a1, bfB, acc1, 0, 0, 0);
        }
        if (s < 3) {
#pragma unroll
            for (int j = 0; j < 32; ++j) xa[j] = xb[j];
            idr = idr2; mkr = mkr2;
        }
    }

    // park C fragments (verified C/D layout) and 4-wave block reduce
#pragma unroll
    for (int r = 0; r < 16; ++r) {
        const int mrow = (r & 3) + 8 * (r >> 2) + 4 * half;
        tbl[w][mrow][d32]      = acc0[r];
        tbl[w][32 + mrow][d32] = acc1[r];
    }
    c0 += __shfl_down(c0, 32);
    c1 += __shfl_down(c1, 32);
    if (lane < 32) { lc2[w][lane] = (float)c0; lc2[w][lane + 32] = (float)c1; }
    __syncthreads();

    float* pb = parts + (size_t)blockIdx.x * 2048;
    for (int i = tid; i < 2048; i += 256) {
        const int row = i >> 5, col = i & 31;
        pb[i] = tbl[0][row][col] + tbl[1][row][col]
              + tbl[2][row][col] + tbl[3][row][col];
    }
    if (tid < KK)
        pcnt[(size_t)blockIdx.x * KK + tid] =
            lc2[0][tid] + lc2[1][tid] + lc2[2][tid] + lc2[3][tid];
}

// ---------------------------------------------------------------------------
// Kernel 2: parallel mean-reduce (R14-proven). Also zeroes the K3 ticket.
// ---------------------------------------------------------------------------
__global__ __launch_bounds__(256) void k_mid(
    const float* __restrict__ parts, const float* __restrict__ pcnt,
    float* __restrict__ mu, int* bar)
{
    const int gb  = blockIdx.x;          // 0..255
    const int b   = gb >> 4, seg = gb & 15;
    const int tid = threadIdx.x;
    __shared__ float red2[2][128];
    __shared__ float rc4[4];
    if (gb == 0 && tid == 0) bar[0] = 0;         // ticket reset for K3

    const int k0 = seg * 4;
    {   // counts: wave w -> k = k0 + w
        const int w = tid >> 6, lane = tid & 63;
        float cv = pcnt[((size_t)(b * K1_BPB + lane)) * KK + k0 + w];
        for (int off = 32; off; off >>= 1) cv += __shfl_down(cv, off);
        if (lane == 0) {
            mu[((size_t)b * KK + k0 + w) * 36 + 32] = cv;
            const float rc = 1.f / fmaxf(cv, 1.f);
            mu[((size_t)b * KK + k0 + w) * 36 + 33] = rc;
            rc4[w] = rc;
        }
    }
    const int e  = seg * 128 + (tid & 127);
    const int jh = tid >> 7;             // 0 / 1
    float s = 0.f;
    const float* pp = parts + ((size_t)(b * K1_BPB + jh * 32)) * 2048 + e;
#pragma unroll 4
    for (int j = 0; j < 32; ++j) s += pp[(size_t)j * 2048];
    red2[jh][tid & 127] = s;
    __syncthreads();
    if (tid < 128) {
        const int k = e >> 5;
        mu[((size_t)b * KK + k) * 36 + (e & 31)] =
            (red2[0][tid] + red2[1][tid]) * rc4[k - k0];
    }
}

// ---------------------------------------------------------------------------
// Kernel 3: pull pass + designated-block push/reg + last-ticket final
// (R14-proven).
// ---------------------------------------------------------------------------
#define K2_BPB 64
#define K2_PTS 1024
#define GRID3 (BB * K2_BPB)              // 1024

__global__ __launch_bounds__(256) void k_pull_final(
    const float* __restrict__ emb, const int* __restrict__ ids,
    const int* __restrict__ mask, const float* __restrict__ mu,
    float* varpart, float* aux, int* bar, float* __restrict__ out)
{
    __shared__ float smu[KK][36];
    __shared__ float red[4];
    __shared__ float part[256];
    __shared__ float sf[4][BB];
    __shared__ int s_last;
    const int tid = threadIdx.x;
    const int w = tid >> 6, lane = tid & 63;
    const int pl = lane >> 3;
    const int pc = lane & 7;
    const int b   = blockIdx.x >> 6;
    const int blk = blockIdx.x & 63;

    const float* mub = mu + (size_t)b * KK * 36;
    for (int i = tid; i < KK * 36; i += 256) ((float*)smu)[i] = mub[i];
    __syncthreads();

    // ---- designated block per batch: reg + push losses from smu ----
    if (blk == 0) {
        float ninst = 0.f;
        if (tid < KK) {
            const float c = smu[tid][32];
            const float pres = (c > 0.f) ? 1.f : 0.f;
            float sq = 0.f;
#pragma unroll
            for (int d = 0; d < DD; ++d) { const float m = smu[tid][d]; sq = fmaf(m, m, sq); }
            float nm = ((sq > 0.f) ? sqrtf(sq) : 0.f) * pres;
            float pn = pres;
            for (int off = 32; off; off >>= 1) {
                pn += __shfl_down(pn, off);
                nm += __shfl_down(nm, off);
            }
            if (tid == 0) {
                ninst = pn;
                aux[b]      = nm / fmaxf(pn, 1.f);   // reg_b
                aux[32 + b] = pn;                    // num_inst
            }
        }
        float acc = 0.f;
        for (int idx = tid; idx < KK * KK; idx += 256) {
            const int i = idx >> 6, j = idx & 63;
            if (i < j && smu[i][32] > 0.f && smu[j][32] > 0.f) {
                float dsq = 0.f;
#pragma unroll
                for (int d = 0; d < DD; ++d) {
                    const float df = smu[i][d] - smu[j][d];
                    dsq = fmaf(df, df, dsq);
                }
                const float pd = (dsq > 0.f) ? sqrtf(dsq) : 0.f;
                const float pen = fmaxf(2.f * DELTA_D - pd, 0.f);
                acc = fmaf(pen, pen, acc);
            }
        }
        for (int off = 32; off; off >>= 1) acc += __shfl_down(acc, off);
        if ((tid & 63) == 0) red[tid >> 6] = acc;
        __syncthreads();
        if (tid == 0) {
            const float tot = red[0] + red[1] + red[2] + red[3];
            const float ni = aux[32 + b];
            const float np = ni * (ni - 1.f) * 0.5f;
            aux[16 + b] = tot / fmaxf(np, 1.f);      // dist_b
        }
        __syncthreads();                  // red free for pull reuse
    }

    // ---- pull pass (R11-proven, fully coalesced) ----
    const size_t p0 = (size_t)b * NN + (size_t)blk * K2_PTS + (size_t)w * 256;
    float accv = 0.f;
    for (int t = 0; t < 4; ++t) {
        const size_t pt0 = p0 + t * 64;
        const int idr = ids[pt0 + lane];
        const int mkr = mask[pt0 + lane];
        const int vid = (mkr != 0 && (unsigned)idr < KK) ? idr : -1;
        const float4* ep4 = (const float4*)(emb + pt0 * DD);
#pragma unroll
        for (int g = 0; g < 8; ++g) {
            const float4 x = ep4[g * 64 + lane];
            const int sid = __shfl(vid, g * 8 + pl);
            const int row = (sid >= 0) ? sid : 0;
            const float4 m4 = *(const float4*)&smu[row][4 * pc];
            float a = x.x - m4.x; float dsq = a * a;
            a = x.y - m4.y; dsq = fmaf(a, a, dsq);
            a = x.z - m4.z; dsq = fmaf(a, a, dsq);
            a = x.w - m4.w; dsq = fmaf(a, a, dsq);
            dsq += __shfl_xor(dsq, 1);
            dsq += __shfl_xor(dsq, 2);
            dsq += __shfl_xor(dsq, 4);
            if (pc == 0 && sid >= 0) {
                const float dist = (dsq > 0.f) ? sqrtf(dsq) : 0.f;
                float pen = fmaxf(dist - DELTA_V, 0.f);
                accv = fmaf(pen * pen, smu[row][33], accv);
            }
        }
    }
    for (int off = 32; off; off >>= 1) accv += __shfl_down(accv, off);
    if (lane == 0) red[w] = accv;
    __syncthreads();
    if (tid == 0)
        varpart[blockIdx.x] = red[0] + red[1] + red[2] + red[3];

    // ---- last-arrival ticket: combine (R9-proven protocol) ----
    if (tid == 0) {
        const int ret = __hip_atomic_fetch_add(bar, 1, __ATOMIC_RELEASE,
                                               __HIP_MEMORY_SCOPE_AGENT);
        s_last = (ret == GRID3 - 1) ? 1 : 0;
        if (s_last)
            (void)__hip_atomic_load(bar, __ATOMIC_ACQUIRE,
                                    __HIP_MEMORY_SCOPE_AGENT);
    }
    __syncthreads();
    if (s_last) {
        {   // each thread sums 4 varpart entries (coalesced float4)
            const float4 v4 = ((const float4*)varpart)[tid];
            part[tid] = v4.x + v4.y + v4.z + v4.w;
        }
        __syncthreads();
        if (tid < BB) {
            float vs = 0.f;
#pragma unroll
            for (int j = 0; j < 16; ++j) vs += part[tid * 16 + j];
            const float ni = aux[32 + tid];
            sf[0][tid] = vs / fmaxf(ni, 1.f);
            sf[1][tid] = (ni >= 2.f) ? 1.f : 0.f;
            sf[2][tid] = aux[tid];
            sf[3][tid] = aux[16 + tid];
        }
        __syncthreads();
        if (tid == 0) {
            float denom = 0.f, v = 0.f, d = 0.f, r = 0.f;
            for (int bb = 0; bb < BB; ++bb) {
                const float vb = sf[1][bb];
                denom += vb;
                v += sf[0][bb] * vb;
                d += sf[3][bb] * vb;
                r += sf[2][bb] * vb;
            }
            denom = fmaxf(denom, 1.f);
            v /= denom; d /= denom; r /= denom;
            out[0] = v + d + 0.001f * r;   // ALPHA=BETA=1, GAMMA=0.001
            out[1] = v;
            out[2] = d;
            out[3] = r;
        }
    }
}

// ---------------------------------------------------------------------------
extern "C" void kernel_launch(void* const* d_in, const int* in_sizes, int n_in,
                              void* d_out, int out_size, void* d_ws, size_t ws_size,
                              hipStream_t stream)
{
    const float* emb  = (const float*)d_in[0];
    const int*   ids  = (const int*)d_in[1];
    const int*   mask = (const int*)d_in[2];   // bool widened to int32

    float* ws      = (float*)d_ws;
    float* parts   = ws;                                        // 1024*2048
    float* pcnt    = parts + (size_t)BB * K1_BPB * KK * DD;     // 1024*64
    float* mu      = pcnt + (size_t)BB * K1_BPB * KK;           // 16*64*36
    float* varpart = mu + (size_t)BB * KK * 36;                 // 1024
    float* aux     = varpart + GRID3;                           // 48
    int*   bar     = (int*)(aux + 64);                          // 1 ticket

    k_accum<<<BB * K1_BPB, 256, 0, stream>>>(emb, ids, mask, parts, pcnt);
    k_mid<<<256, 256, 0, stream>>>(parts, pcnt, mu, bar);
    k_pull_final<<<GRID3, 256, 0, stream>>>(emb, ids, mask, mu, varpart,
                                            aux, bar, (float*)d_out);
}